// Round 26
// baseline (319.188 us; speedup 1.0000x reference)
//
#include <hip/hip_runtime.h>
#include <hip/hip_fp16.h>

// GCN link classifier, CSR-gather aggregation, bucketed CSR (64 slots/node).
// R26: consolidation — k_edge single dispatch (restores L2 table sharing),
//      fill sweeps 4->2 (halves edge-list re-reads).
// Pipeline (7 dispatches):
//   memset cursor; k_fill x2; k_prep(dinv+prescale); k_gather_h->agg1;
//   k_mlp1->xl2s(fp16); k_gather_h->agg2; k_mlp2->gt,gb; k_edge -> out

#define HIDN 32
#define CAP 64

struct __align__(8) Half4 { __half2 a, b; };

// sweep-partitioned fill into fixed 64-slot buckets; cursor counts degree.
__global__ void k_fill_sweep(const int* __restrict__ src, const int* __restrict__ dst,
                             int E, int lo, int hi,
                             int* __restrict__ cursor, int* __restrict__ csr) {
    int e = blockIdx.x * blockDim.x + threadIdx.x;
    if (e >= E) return;
    int d = __builtin_nontemporal_load(dst + e);
    if (d >= lo && d < hi) {
        int j = atomicAdd(&cursor[d], 1);
        if (j < CAP) csr[(size_t)d * CAP + j] = __builtin_nontemporal_load(src + e);
    }
}

// dinv = rsqrt(deg+1); prescale xs = fp16(dinv * x). 256 nodes/block.
__global__ void k_prep(const int* __restrict__ cursor, int N,
                       float* __restrict__ dinv,
                       const float4* __restrict__ x4, Half4* __restrict__ xs4) {
    __shared__ float dsh[256];
    int t = threadIdx.x, i = blockIdx.x * 256 + t;
    int v = (i < N) ? cursor[i] : 0;
    float dv = rsqrtf((float)(v + 1));       // +1 = self loop
    if (i < N) dinv[i] = dv;
    dsh[t] = dv;
    __syncthreads();
#pragma unroll
    for (int it = 0; it < 8; ++it) {
        int q = it * 256 + t;                // quad within block
        int g = blockIdx.x * (256 * 8) + q;
        if (g < N * 8) {
            float w = dsh[q >> 3];
            float4 a = x4[g];
            Half4 hv;
            hv.a = __floats2half2_rn(a.x * w, a.y * w);
            hv.b = __floats2half2_rn(a.z * w, a.w * w);
            xs4[g] = hv;
        }
    }
}

#define ADD8(raw)                                        \
    {                                                    \
        const __half2* _h = (const __half2*)&(raw);      \
        float2 _f;                                       \
        _f = __half22float2(_h[0]); a0 += _f.x; a1 += _f.y; \
        _f = __half22float2(_h[1]); a2 += _f.x; a3 += _f.y; \
        _f = __half22float2(_h[2]); a4 += _f.x; a5 += _f.y; \
        _f = __half22float2(_h[3]); a6 += _f.x; a7 += _f.y; \
    }

// agg[i] = dinv[i] * ( tbl[i] + Sum_{s in bucket(i)} tbl[s] )
// fp16 table (64B rows); 4 threads/node; unroll-4 independent row loads.
__global__ void k_gather_h(const float4* __restrict__ tbl, const float* __restrict__ dinv,
                           const int* __restrict__ cnt, const int* __restrict__ csr,
                           int N, float4* __restrict__ out) {
    int t = blockIdx.x * blockDim.x + threadIdx.x;   // N*4
    if (t >= N * 4) return;
    int i = t >> 2, c = t & 3;
    float di = dinv[i];
    float a0 = 0.f, a1 = 0.f, a2 = 0.f, a3 = 0.f;
    float a4 = 0.f, a5 = 0.f, a6 = 0.f, a7 = 0.f;
    {
        float4 raw = tbl[(size_t)i * 4 + c];         // self-loop term
        ADD8(raw);
    }
    int deg = cnt[i];
    int p = i * CAP;
    int end = p + (deg < CAP ? deg : CAP);
    for (; p + 3 < end; p += 4) {
        int s0 = __builtin_nontemporal_load(csr + p);
        int s1 = __builtin_nontemporal_load(csr + p + 1);
        int s2 = __builtin_nontemporal_load(csr + p + 2);
        int s3 = __builtin_nontemporal_load(csr + p + 3);
        float4 r0 = tbl[(size_t)s0 * 4 + c];
        float4 r1 = tbl[(size_t)s1 * 4 + c];
        float4 r2 = tbl[(size_t)s2 * 4 + c];
        float4 r3 = tbl[(size_t)s3 * 4 + c];
        ADD8(r0); ADD8(r1); ADD8(r2); ADD8(r3);
    }
    for (; p < end; ++p) {
        float4 r = tbl[(size_t)__builtin_nontemporal_load(csr + p) * 4 + c];
        ADD8(r);
    }
    out[(size_t)i * 8 + 2 * c]     = make_float4(a0 * di, a1 * di, a2 * di, a3 * di);
    out[(size_t)i * 8 + 2 * c + 1] = make_float4(a4 * di, a5 * di, a6 * di, a7 * di);
}

// ---- k_mlp1 v5: 32 nodes/block, 256 threads (4 nodes x 4 outs / thread),
// 12.9 KB LDS (aT fp32 4.2K + hT16 fp16 8.7K) for occupancy.
__global__ __launch_bounds__(256) void k_mlp1(
        const float4* __restrict__ agg1, const float* __restrict__ dinv,
        const float* __restrict__ W1, const float* __restrict__ b1,
        const float* __restrict__ W2, int N, __half* __restrict__ xl2s) {
    __shared__ float aT[32][33];       // acts transposed [feat][node]
    __shared__ __half hT16[32][136];   // h1 [node][feat], fp16
    int t = threadIdx.x;
    int base = blockIdx.x * 32;
    {
        int n = t >> 3, q = t & 7;               // 256 = 32 nodes x 8 quads
        int gi = base + n;
        float4 v = (gi < N) ? agg1[(size_t)gi * 8 + q] : make_float4(0.f, 0.f, 0.f, 0.f);
        aT[q * 4 + 0][n] = v.x; aT[q * 4 + 1][n] = v.y;
        aT[q * 4 + 2][n] = v.z; aT[q * 4 + 3][n] = v.w;
    }
    __syncthreads();
    int j = t & 31, r = t >> 5;      // r: 0..7, node quad
    int n0 = r * 4;
    float acc[4][4];
    {
        float4 bq = *reinterpret_cast<const float4*>(&b1[4 * j]);
#pragma unroll
        for (int n = 0; n < 4; ++n) {
            acc[n][0] = bq.x; acc[n][1] = bq.y; acc[n][2] = bq.z; acc[n][3] = bq.w;
        }
    }
#pragma unroll
    for (int k = 0; k < 32; ++k) {
        float4 w = *reinterpret_cast<const float4*>(&W1[k * 128 + 4 * j]);
#pragma unroll
        for (int n = 0; n < 4; ++n) {
            float a = aT[k][n0 + n];
            acc[n][0] = fmaf(a, w.x, acc[n][0]);
            acc[n][1] = fmaf(a, w.y, acc[n][1]);
            acc[n][2] = fmaf(a, w.z, acc[n][2]);
            acc[n][3] = fmaf(a, w.w, acc[n][3]);
        }
    }
#pragma unroll
    for (int n = 0; n < 4; ++n) {
        Half4 hv;
        hv.a = __floats2half2_rn(fmaxf(acc[n][0], 0.f), fmaxf(acc[n][1], 0.f));
        hv.b = __floats2half2_rn(fmaxf(acc[n][2], 0.f), fmaxf(acc[n][3], 0.f));
        *reinterpret_cast<Half4*>(&hT16[n0 + n][4 * j]) = hv;
    }
    __syncthreads();
    int jo = j & 7, ko = j >> 3;
    float acc2[4][4];
#pragma unroll
    for (int n = 0; n < 4; ++n) { acc2[n][0] = acc2[n][1] = acc2[n][2] = acc2[n][3] = 0.f; }
#pragma unroll
    for (int kk = 0; kk < 8; ++kk) {
        int kbase = ko * 32 + 4 * kk;
        float2 hf[4][2];
#pragma unroll
        for (int n = 0; n < 4; ++n) {
            Half4 hv = *reinterpret_cast<const Half4*>(&hT16[n0 + n][kbase]);
            hf[n][0] = __half22float2(hv.a);
            hf[n][1] = __half22float2(hv.b);
        }
#pragma unroll
        for (int c = 0; c < 4; ++c) {
            float4 w = *reinterpret_cast<const float4*>(&W2[(kbase + c) * 32 + 4 * jo]);
#pragma unroll
            for (int n = 0; n < 4; ++n) {
                float a = (c == 0) ? hf[n][0].x : (c == 1) ? hf[n][0].y
                        : (c == 2) ? hf[n][1].x : hf[n][1].y;
                acc2[n][0] = fmaf(a, w.x, acc2[n][0]);
                acc2[n][1] = fmaf(a, w.y, acc2[n][1]);
                acc2[n][2] = fmaf(a, w.z, acc2[n][2]);
                acc2[n][3] = fmaf(a, w.w, acc2[n][3]);
            }
        }
    }
#pragma unroll
    for (int n = 0; n < 4; ++n)
#pragma unroll
        for (int c = 0; c < 4; ++c) {
            acc2[n][c] += __shfl_xor(acc2[n][c], 8);
            acc2[n][c] += __shfl_xor(acc2[n][c], 16);
        }
    if (ko == 0) {
#pragma unroll
        for (int n = 0; n < 4; ++n) {
            int gi = base + n0 + n;
            if (gi < N) {
                float d = dinv[gi];
                Half4 hv;
                hv.a = __floats2half2_rn(acc2[n][0] * d, acc2[n][1] * d);
                hv.b = __floats2half2_rn(acc2[n][2] * d, acc2[n][3] * d);
                *reinterpret_cast<Half4*>(&xl2s[(size_t)gi * 32 + 4 * jo]) = hv;
            }
        }
    }
}

// ---- k_mlp2 v3: 32 nodes/block, 256 threads (2 nodes x 4 outs / thread),
// fp32 hT [32][33] (4.2 KB LDS), acc[2][4] => low VGPR.
__global__ __launch_bounds__(256) void k_mlp2(
        const float4* __restrict__ agg2, const float* __restrict__ b2,
        const float* __restrict__ Wm1, int N,
        __half* __restrict__ gt, __half* __restrict__ gb) {
    __shared__ float hT[32][33];     // h2 transposed [feat][node]
    int t = threadIdx.x;
    int base = blockIdx.x * 32;
    const float4* b2q = reinterpret_cast<const float4*>(b2);
    {
        int n = t >> 3, q = t & 7;               // 256 = 32 nodes x 8 quads
        int gi = base + n;
        float4 v = (gi < N) ? agg2[(size_t)gi * 8 + q] : make_float4(0.f, 0.f, 0.f, 0.f);
        float4 bb = b2q[q];
        hT[q * 4 + 0][n] = fmaxf(v.x + bb.x, 0.f);
        hT[q * 4 + 1][n] = fmaxf(v.y + bb.y, 0.f);
        hT[q * 4 + 2][n] = fmaxf(v.z + bb.z, 0.f);
        hT[q * 4 + 3][n] = fmaxf(v.w + bb.w, 0.f);
    }
    __syncthreads();
    int j = t & 15, r = t >> 4;      // r: node pair (0..15), j: out quad of [gt|gb]
    int n0 = r * 2;
    int half = j >> 3, jo = j & 7;
    float acc[2][4];
#pragma unroll
    for (int n = 0; n < 2; ++n) { acc[n][0] = acc[n][1] = acc[n][2] = acc[n][3] = 0.f; }
#pragma unroll
    for (int k = 0; k < 32; ++k) {
        float4 w = *reinterpret_cast<const float4*>(&Wm1[(k + half * 32) * 32 + 4 * jo]);
#pragma unroll
        for (int n = 0; n < 2; ++n) {
            float a = hT[k][n0 + n];
            acc[n][0] = fmaf(a, w.x, acc[n][0]);
            acc[n][1] = fmaf(a, w.y, acc[n][1]);
            acc[n][2] = fmaf(a, w.z, acc[n][2]);
            acc[n][3] = fmaf(a, w.w, acc[n][3]);
        }
    }
    __half* dsttab = half ? gb : gt;
#pragma unroll
    for (int n = 0; n < 2; ++n) {
        int gi = base + n0 + n;
        if (gi < N) {
            Half4 hv;
            hv.a = __floats2half2_rn(acc[n][0], acc[n][1]);
            hv.b = __floats2half2_rn(acc[n][2], acc[n][3]);
            *reinterpret_cast<Half4*>(&dsttab[(size_t)gi * 32 + 4 * jo]) = hv;
        }
    }
}

// out[e] = relu(gt[u] + gb[v] + bm1) @ Wm2 + bm2
// Single dispatch; 2 edges per thread, 4 lanes per edge.
__global__ void k_edge(const int* __restrict__ ps, const int* __restrict__ pd, int Ep,
                       const int* __restrict__ ns, const int* __restrict__ nd, int En,
                       int P,
                       const float4* __restrict__ gt4, const float4* __restrict__ gb4,
                       const float* __restrict__ bm1, const float* __restrict__ Wm2,
                       const float* __restrict__ bm2, float* __restrict__ out) {
    int t = blockIdx.x * blockDim.x + threadIdx.x;   // P*4 threads
    int p = t >> 2, q = t & 3;
    if (p >= P) return;
    int E = Ep + En;
    int e0 = p, e1 = p + P;
    int u0, v0;
    if (e0 < Ep) { u0 = __builtin_nontemporal_load(ps + e0); v0 = __builtin_nontemporal_load(pd + e0); }
    else         { u0 = __builtin_nontemporal_load(ns + (e0 - Ep)); v0 = __builtin_nontemporal_load(nd + (e0 - Ep)); }
    bool has1 = (e1 < E);
    int u1 = u0, v1 = v0;
    if (has1) {
        if (e1 < Ep) { u1 = __builtin_nontemporal_load(ps + e1); v1 = __builtin_nontemporal_load(pd + e1); }
        else         { u1 = __builtin_nontemporal_load(ns + (e1 - Ep)); v1 = __builtin_nontemporal_load(nd + (e1 - Ep)); }
    }
    float4 a0raw = gt4[(size_t)u0 * 4 + q];
    float4 b0raw = gb4[(size_t)v0 * 4 + q];
    float4 a1raw = gt4[(size_t)u1 * 4 + q];
    float4 b1raw = gb4[(size_t)v1 * 4 + q];
    const __half* a0h = (const __half*)&a0raw;
    const __half* b0h = (const __half*)&b0raw;
    const __half* a1h = (const __half*)&a1raw;
    const __half* b1h = (const __half*)&b1raw;
    int k0 = q * 8;
    float o00 = 0.f, o01 = 0.f, o10 = 0.f, o11 = 0.f;
#pragma unroll
    for (int r = 0; r < 8; ++r) {
        float bm = bm1[k0 + r];
        float w0 = Wm2[(k0 + r) * 2 + 0];
        float w1 = Wm2[(k0 + r) * 2 + 1];
        float h0 = fmaxf(__half2float(a0h[r]) + __half2float(b0h[r]) + bm, 0.f);
        o00 = fmaf(h0, w0, o00); o01 = fmaf(h0, w1, o01);
        float h1 = fmaxf(__half2float(a1h[r]) + __half2float(b1h[r]) + bm, 0.f);
        o10 = fmaf(h1, w0, o10); o11 = fmaf(h1, w1, o11);
    }
    o00 += __shfl_down(o00, 2, 4); o01 += __shfl_down(o01, 2, 4);
    o00 += __shfl_down(o00, 1, 4); o01 += __shfl_down(o01, 1, 4);
    o10 += __shfl_down(o10, 2, 4); o11 += __shfl_down(o11, 2, 4);
    o10 += __shfl_down(o10, 1, 4); o11 += __shfl_down(o11, 1, 4);
    if (q == 0) {
        float c0 = bm2[0], c1 = bm2[1];
        __builtin_nontemporal_store(o00 + c0, out + (size_t)e0 * 2 + 0);
        __builtin_nontemporal_store(o01 + c1, out + (size_t)e0 * 2 + 1);
        if (has1) {
            __builtin_nontemporal_store(o10 + c0, out + (size_t)e1 * 2 + 0);
            __builtin_nontemporal_store(o11 + c1, out + (size_t)e1 * 2 + 1);
        }
    }
}

extern "C" void kernel_launch(void* const* d_in, const int* in_sizes, int n_in,
                              void* d_out, int out_size, void* d_ws, size_t ws_size,
                              hipStream_t stream) {
    const float* x   = (const float*)d_in[0];
    const int*   pei = (const int*)d_in[1];
    const int*   nei = (const int*)d_in[2];
    const float* W1  = (const float*)d_in[3];
    const float* b1  = (const float*)d_in[4];
    const float* W2  = (const float*)d_in[5];
    const float* b2  = (const float*)d_in[6];
    const float* Wm1 = (const float*)d_in[7];
    const float* bm1 = (const float*)d_in[8];
    const float* Wm2 = (const float*)d_in[9];
    const float* bm2 = (const float*)d_in[10];

    const int N  = in_sizes[0] / HIDN;
    const int Ep = in_sizes[1] / 2;
    const int En = in_sizes[2] / 2;
    const int* ps = pei;            // pos src
    const int* pd = pei + Ep;       // pos dst
    const int* ns = nei;
    const int* nd = nei + En;

    // workspace layout (256B-aligned slabs)
    char* ws = (char*)d_ws;
    size_t off = 0;
    auto alloc = [&](size_t bytes) { size_t o = off; off += (bytes + 255) & ~(size_t)255; return o; };
    int*    cursor = (int*)(ws + alloc((size_t)N * 4));
    int*    csr    = (int*)(ws + alloc((size_t)N * CAP * 4));
    float*  dinv   = (float*)(ws + alloc((size_t)N * 4));
    __half* xs     = (__half*)(ws + alloc((size_t)N * HIDN * 2));
    float*  agg1   = (float*)(ws + alloc((size_t)N * HIDN * 4));
    __half* xl2s   = (__half*)(ws + alloc((size_t)N * HIDN * 2));
    float*  agg2   = (float*)(ws + alloc((size_t)N * HIDN * 4));
    __half* gt     = (__half*)(ws + alloc((size_t)N * HIDN * 2));
    __half* gb     = (__half*)(ws + alloc((size_t)N * HIDN * 2));

    // ---- bucketed CSR build: 2 dst-range sweeps ----
    hipMemsetAsync(cursor, 0, (size_t)N * 4, stream);
    {
        int grid = (Ep + 255) / 256;
        for (int s = 0; s < 2; ++s) {
            int lo = (int)((size_t)N * s / 2);
            int hi = (int)((size_t)N * (s + 1) / 2);
            k_fill_sweep<<<grid, 256, 0, stream>>>(ps, pd, Ep, lo, hi, cursor, csr);
        }
    }
    k_prep<<<(N + 255) / 256, 256, 0, stream>>>(cursor, N, dinv,
                                                (const float4*)x, (Half4*)xs);

    // ---- layer 1 ----
    k_gather_h<<<(N * 4 + 255) / 256, 256, 0, stream>>>(
        (const float4*)xs, dinv, cursor, csr, N, (float4*)agg1);
    k_mlp1<<<(N + 31) / 32, 256, 0, stream>>>(
        (const float4*)agg1, dinv, W1, b1, W2, N, xl2s);

    // ---- layer 2 ----
    k_gather_h<<<(N * 4 + 255) / 256, 256, 0, stream>>>(
        (const float4*)xl2s, dinv, cursor, csr, N, (float4*)agg2);
    k_mlp2<<<(N + 31) / 32, 256, 0, stream>>>(
        (const float4*)agg2, b2, Wm1, N, gt, gb);

    // ---- edge MLP over pos+neg edges (single dispatch) ----
    {
        int E = Ep + En;
        int P = (E + 1) / 2;
        size_t threads = (size_t)P * 4;
        k_edge<<<(int)((threads + 255) / 256), 256, 0, stream>>>(
            ps, pd, Ep, ns, nd, En, P,
            (const float4*)gt, (const float4*)gb,
            bm1, Wm2, bm2, (float*)d_out);
    }
}

// Round 27
// 309.515 us; speedup vs baseline: 1.0313x; 1.0313x over previous
//
#include <hip/hip_runtime.h>
#include <hip/hip_fp16.h>

// GCN link classifier, CSR-gather aggregation, bucketed CSR (64 slots/node).
// R27: best-of combination — 4 fill sweeps (R25; 2 sweeps re-amplified writes)
//      + single k_edge dispatch (R26; restores full-table L2 sharing).
// Pipeline (9 dispatches):
//   memset cursor; k_fill x4; k_prep(dinv+prescale); k_gather_h->agg1;
//   k_mlp1->xl2s(fp16); k_gather_h->agg2; k_mlp2->gt,gb; k_edge -> out

#define HIDN 32
#define CAP 64

struct __align__(8) Half4 { __half2 a, b; };

// sweep-partitioned fill into fixed 64-slot buckets; cursor counts degree.
__global__ void k_fill_sweep(const int* __restrict__ src, const int* __restrict__ dst,
                             int E, int lo, int hi,
                             int* __restrict__ cursor, int* __restrict__ csr) {
    int e = blockIdx.x * blockDim.x + threadIdx.x;
    if (e >= E) return;
    int d = __builtin_nontemporal_load(dst + e);
    if (d >= lo && d < hi) {
        int j = atomicAdd(&cursor[d], 1);
        if (j < CAP) csr[(size_t)d * CAP + j] = __builtin_nontemporal_load(src + e);
    }
}

// dinv = rsqrt(deg+1); prescale xs = fp16(dinv * x). 256 nodes/block.
__global__ void k_prep(const int* __restrict__ cursor, int N,
                       float* __restrict__ dinv,
                       const float4* __restrict__ x4, Half4* __restrict__ xs4) {
    __shared__ float dsh[256];
    int t = threadIdx.x, i = blockIdx.x * 256 + t;
    int v = (i < N) ? cursor[i] : 0;
    float dv = rsqrtf((float)(v + 1));       // +1 = self loop
    if (i < N) dinv[i] = dv;
    dsh[t] = dv;
    __syncthreads();
#pragma unroll
    for (int it = 0; it < 8; ++it) {
        int q = it * 256 + t;                // quad within block
        int g = blockIdx.x * (256 * 8) + q;
        if (g < N * 8) {
            float w = dsh[q >> 3];
            float4 a = x4[g];
            Half4 hv;
            hv.a = __floats2half2_rn(a.x * w, a.y * w);
            hv.b = __floats2half2_rn(a.z * w, a.w * w);
            xs4[g] = hv;
        }
    }
}

#define ADD8(raw)                                        \
    {                                                    \
        const __half2* _h = (const __half2*)&(raw);      \
        float2 _f;                                       \
        _f = __half22float2(_h[0]); a0 += _f.x; a1 += _f.y; \
        _f = __half22float2(_h[1]); a2 += _f.x; a3 += _f.y; \
        _f = __half22float2(_h[2]); a4 += _f.x; a5 += _f.y; \
        _f = __half22float2(_h[3]); a6 += _f.x; a7 += _f.y; \
    }

// agg[i] = dinv[i] * ( tbl[i] + Sum_{s in bucket(i)} tbl[s] )
// fp16 table (64B rows); 4 threads/node; unroll-4 independent row loads.
__global__ void k_gather_h(const float4* __restrict__ tbl, const float* __restrict__ dinv,
                           const int* __restrict__ cnt, const int* __restrict__ csr,
                           int N, float4* __restrict__ out) {
    int t = blockIdx.x * blockDim.x + threadIdx.x;   // N*4
    if (t >= N * 4) return;
    int i = t >> 2, c = t & 3;
    float di = dinv[i];
    float a0 = 0.f, a1 = 0.f, a2 = 0.f, a3 = 0.f;
    float a4 = 0.f, a5 = 0.f, a6 = 0.f, a7 = 0.f;
    {
        float4 raw = tbl[(size_t)i * 4 + c];         // self-loop term
        ADD8(raw);
    }
    int deg = cnt[i];
    int p = i * CAP;
    int end = p + (deg < CAP ? deg : CAP);
    for (; p + 3 < end; p += 4) {
        int s0 = __builtin_nontemporal_load(csr + p);
        int s1 = __builtin_nontemporal_load(csr + p + 1);
        int s2 = __builtin_nontemporal_load(csr + p + 2);
        int s3 = __builtin_nontemporal_load(csr + p + 3);
        float4 r0 = tbl[(size_t)s0 * 4 + c];
        float4 r1 = tbl[(size_t)s1 * 4 + c];
        float4 r2 = tbl[(size_t)s2 * 4 + c];
        float4 r3 = tbl[(size_t)s3 * 4 + c];
        ADD8(r0); ADD8(r1); ADD8(r2); ADD8(r3);
    }
    for (; p < end; ++p) {
        float4 r = tbl[(size_t)__builtin_nontemporal_load(csr + p) * 4 + c];
        ADD8(r);
    }
    out[(size_t)i * 8 + 2 * c]     = make_float4(a0 * di, a1 * di, a2 * di, a3 * di);
    out[(size_t)i * 8 + 2 * c + 1] = make_float4(a4 * di, a5 * di, a6 * di, a7 * di);
}

// ---- k_mlp1 v5: 32 nodes/block, 256 threads (4 nodes x 4 outs / thread),
// 12.9 KB LDS (aT fp32 4.2K + hT16 fp16 8.7K) for occupancy.
__global__ __launch_bounds__(256) void k_mlp1(
        const float4* __restrict__ agg1, const float* __restrict__ dinv,
        const float* __restrict__ W1, const float* __restrict__ b1,
        const float* __restrict__ W2, int N, __half* __restrict__ xl2s) {
    __shared__ float aT[32][33];       // acts transposed [feat][node]
    __shared__ __half hT16[32][136];   // h1 [node][feat], fp16
    int t = threadIdx.x;
    int base = blockIdx.x * 32;
    {
        int n = t >> 3, q = t & 7;               // 256 = 32 nodes x 8 quads
        int gi = base + n;
        float4 v = (gi < N) ? agg1[(size_t)gi * 8 + q] : make_float4(0.f, 0.f, 0.f, 0.f);
        aT[q * 4 + 0][n] = v.x; aT[q * 4 + 1][n] = v.y;
        aT[q * 4 + 2][n] = v.z; aT[q * 4 + 3][n] = v.w;
    }
    __syncthreads();
    int j = t & 31, r = t >> 5;      // r: 0..7, node quad
    int n0 = r * 4;
    float acc[4][4];
    {
        float4 bq = *reinterpret_cast<const float4*>(&b1[4 * j]);
#pragma unroll
        for (int n = 0; n < 4; ++n) {
            acc[n][0] = bq.x; acc[n][1] = bq.y; acc[n][2] = bq.z; acc[n][3] = bq.w;
        }
    }
#pragma unroll
    for (int k = 0; k < 32; ++k) {
        float4 w = *reinterpret_cast<const float4*>(&W1[k * 128 + 4 * j]);
#pragma unroll
        for (int n = 0; n < 4; ++n) {
            float a = aT[k][n0 + n];
            acc[n][0] = fmaf(a, w.x, acc[n][0]);
            acc[n][1] = fmaf(a, w.y, acc[n][1]);
            acc[n][2] = fmaf(a, w.z, acc[n][2]);
            acc[n][3] = fmaf(a, w.w, acc[n][3]);
        }
    }
#pragma unroll
    for (int n = 0; n < 4; ++n) {
        Half4 hv;
        hv.a = __floats2half2_rn(fmaxf(acc[n][0], 0.f), fmaxf(acc[n][1], 0.f));
        hv.b = __floats2half2_rn(fmaxf(acc[n][2], 0.f), fmaxf(acc[n][3], 0.f));
        *reinterpret_cast<Half4*>(&hT16[n0 + n][4 * j]) = hv;
    }
    __syncthreads();
    int jo = j & 7, ko = j >> 3;
    float acc2[4][4];
#pragma unroll
    for (int n = 0; n < 4; ++n) { acc2[n][0] = acc2[n][1] = acc2[n][2] = acc2[n][3] = 0.f; }
#pragma unroll
    for (int kk = 0; kk < 8; ++kk) {
        int kbase = ko * 32 + 4 * kk;
        float2 hf[4][2];
#pragma unroll
        for (int n = 0; n < 4; ++n) {
            Half4 hv = *reinterpret_cast<const Half4*>(&hT16[n0 + n][kbase]);
            hf[n][0] = __half22float2(hv.a);
            hf[n][1] = __half22float2(hv.b);
        }
#pragma unroll
        for (int c = 0; c < 4; ++c) {
            float4 w = *reinterpret_cast<const float4*>(&W2[(kbase + c) * 32 + 4 * jo]);
#pragma unroll
            for (int n = 0; n < 4; ++n) {
                float a = (c == 0) ? hf[n][0].x : (c == 1) ? hf[n][0].y
                        : (c == 2) ? hf[n][1].x : hf[n][1].y;
                acc2[n][0] = fmaf(a, w.x, acc2[n][0]);
                acc2[n][1] = fmaf(a, w.y, acc2[n][1]);
                acc2[n][2] = fmaf(a, w.z, acc2[n][2]);
                acc2[n][3] = fmaf(a, w.w, acc2[n][3]);
            }
        }
    }
#pragma unroll
    for (int n = 0; n < 4; ++n)
#pragma unroll
        for (int c = 0; c < 4; ++c) {
            acc2[n][c] += __shfl_xor(acc2[n][c], 8);
            acc2[n][c] += __shfl_xor(acc2[n][c], 16);
        }
    if (ko == 0) {
#pragma unroll
        for (int n = 0; n < 4; ++n) {
            int gi = base + n0 + n;
            if (gi < N) {
                float d = dinv[gi];
                Half4 hv;
                hv.a = __floats2half2_rn(acc2[n][0] * d, acc2[n][1] * d);
                hv.b = __floats2half2_rn(acc2[n][2] * d, acc2[n][3] * d);
                *reinterpret_cast<Half4*>(&xl2s[(size_t)gi * 32 + 4 * jo]) = hv;
            }
        }
    }
}

// ---- k_mlp2 v3: 32 nodes/block, 256 threads (2 nodes x 4 outs / thread),
// fp32 hT [32][33] (4.2 KB LDS), acc[2][4] => low VGPR.
__global__ __launch_bounds__(256) void k_mlp2(
        const float4* __restrict__ agg2, const float* __restrict__ b2,
        const float* __restrict__ Wm1, int N,
        __half* __restrict__ gt, __half* __restrict__ gb) {
    __shared__ float hT[32][33];     // h2 transposed [feat][node]
    int t = threadIdx.x;
    int base = blockIdx.x * 32;
    const float4* b2q = reinterpret_cast<const float4*>(b2);
    {
        int n = t >> 3, q = t & 7;               // 256 = 32 nodes x 8 quads
        int gi = base + n;
        float4 v = (gi < N) ? agg2[(size_t)gi * 8 + q] : make_float4(0.f, 0.f, 0.f, 0.f);
        float4 bb = b2q[q];
        hT[q * 4 + 0][n] = fmaxf(v.x + bb.x, 0.f);
        hT[q * 4 + 1][n] = fmaxf(v.y + bb.y, 0.f);
        hT[q * 4 + 2][n] = fmaxf(v.z + bb.z, 0.f);
        hT[q * 4 + 3][n] = fmaxf(v.w + bb.w, 0.f);
    }
    __syncthreads();
    int j = t & 15, r = t >> 4;      // r: node pair (0..15), j: out quad of [gt|gb]
    int n0 = r * 2;
    int half = j >> 3, jo = j & 7;
    float acc[2][4];
#pragma unroll
    for (int n = 0; n < 2; ++n) { acc[n][0] = acc[n][1] = acc[n][2] = acc[n][3] = 0.f; }
#pragma unroll
    for (int k = 0; k < 32; ++k) {
        float4 w = *reinterpret_cast<const float4*>(&Wm1[(k + half * 32) * 32 + 4 * jo]);
#pragma unroll
        for (int n = 0; n < 2; ++n) {
            float a = hT[k][n0 + n];
            acc[n][0] = fmaf(a, w.x, acc[n][0]);
            acc[n][1] = fmaf(a, w.y, acc[n][1]);
            acc[n][2] = fmaf(a, w.z, acc[n][2]);
            acc[n][3] = fmaf(a, w.w, acc[n][3]);
        }
    }
    __half* dsttab = half ? gb : gt;
#pragma unroll
    for (int n = 0; n < 2; ++n) {
        int gi = base + n0 + n;
        if (gi < N) {
            Half4 hv;
            hv.a = __floats2half2_rn(acc[n][0], acc[n][1]);
            hv.b = __floats2half2_rn(acc[n][2], acc[n][3]);
            *reinterpret_cast<Half4*>(&dsttab[(size_t)gi * 32 + 4 * jo]) = hv;
        }
    }
}

// out[e] = relu(gt[u] + gb[v] + bm1) @ Wm2 + bm2
// Single dispatch; 2 edges per thread, 4 lanes per edge.
__global__ void k_edge(const int* __restrict__ ps, const int* __restrict__ pd, int Ep,
                       const int* __restrict__ ns, const int* __restrict__ nd, int En,
                       int P,
                       const float4* __restrict__ gt4, const float4* __restrict__ gb4,
                       const float* __restrict__ bm1, const float* __restrict__ Wm2,
                       const float* __restrict__ bm2, float* __restrict__ out) {
    int t = blockIdx.x * blockDim.x + threadIdx.x;   // P*4 threads
    int p = t >> 2, q = t & 3;
    if (p >= P) return;
    int E = Ep + En;
    int e0 = p, e1 = p + P;
    int u0, v0;
    if (e0 < Ep) { u0 = __builtin_nontemporal_load(ps + e0); v0 = __builtin_nontemporal_load(pd + e0); }
    else         { u0 = __builtin_nontemporal_load(ns + (e0 - Ep)); v0 = __builtin_nontemporal_load(nd + (e0 - Ep)); }
    bool has1 = (e1 < E);
    int u1 = u0, v1 = v0;
    if (has1) {
        if (e1 < Ep) { u1 = __builtin_nontemporal_load(ps + e1); v1 = __builtin_nontemporal_load(pd + e1); }
        else         { u1 = __builtin_nontemporal_load(ns + (e1 - Ep)); v1 = __builtin_nontemporal_load(nd + (e1 - Ep)); }
    }
    float4 a0raw = gt4[(size_t)u0 * 4 + q];
    float4 b0raw = gb4[(size_t)v0 * 4 + q];
    float4 a1raw = gt4[(size_t)u1 * 4 + q];
    float4 b1raw = gb4[(size_t)v1 * 4 + q];
    const __half* a0h = (const __half*)&a0raw;
    const __half* b0h = (const __half*)&b0raw;
    const __half* a1h = (const __half*)&a1raw;
    const __half* b1h = (const __half*)&b1raw;
    int k0 = q * 8;
    float o00 = 0.f, o01 = 0.f, o10 = 0.f, o11 = 0.f;
#pragma unroll
    for (int r = 0; r < 8; ++r) {
        float bm = bm1[k0 + r];
        float w0 = Wm2[(k0 + r) * 2 + 0];
        float w1 = Wm2[(k0 + r) * 2 + 1];
        float h0 = fmaxf(__half2float(a0h[r]) + __half2float(b0h[r]) + bm, 0.f);
        o00 = fmaf(h0, w0, o00); o01 = fmaf(h0, w1, o01);
        float h1 = fmaxf(__half2float(a1h[r]) + __half2float(b1h[r]) + bm, 0.f);
        o10 = fmaf(h1, w0, o10); o11 = fmaf(h1, w1, o11);
    }
    o00 += __shfl_down(o00, 2, 4); o01 += __shfl_down(o01, 2, 4);
    o00 += __shfl_down(o00, 1, 4); o01 += __shfl_down(o01, 1, 4);
    o10 += __shfl_down(o10, 2, 4); o11 += __shfl_down(o11, 2, 4);
    o10 += __shfl_down(o10, 1, 4); o11 += __shfl_down(o11, 1, 4);
    if (q == 0) {
        float c0 = bm2[0], c1 = bm2[1];
        __builtin_nontemporal_store(o00 + c0, out + (size_t)e0 * 2 + 0);
        __builtin_nontemporal_store(o01 + c1, out + (size_t)e0 * 2 + 1);
        if (has1) {
            __builtin_nontemporal_store(o10 + c0, out + (size_t)e1 * 2 + 0);
            __builtin_nontemporal_store(o11 + c1, out + (size_t)e1 * 2 + 1);
        }
    }
}

extern "C" void kernel_launch(void* const* d_in, const int* in_sizes, int n_in,
                              void* d_out, int out_size, void* d_ws, size_t ws_size,
                              hipStream_t stream) {
    const float* x   = (const float*)d_in[0];
    const int*   pei = (const int*)d_in[1];
    const int*   nei = (const int*)d_in[2];
    const float* W1  = (const float*)d_in[3];
    const float* b1  = (const float*)d_in[4];
    const float* W2  = (const float*)d_in[5];
    const float* b2  = (const float*)d_in[6];
    const float* Wm1 = (const float*)d_in[7];
    const float* bm1 = (const float*)d_in[8];
    const float* Wm2 = (const float*)d_in[9];
    const float* bm2 = (const float*)d_in[10];

    const int N  = in_sizes[0] / HIDN;
    const int Ep = in_sizes[1] / 2;
    const int En = in_sizes[2] / 2;
    const int* ps = pei;            // pos src
    const int* pd = pei + Ep;       // pos dst
    const int* ns = nei;
    const int* nd = nei + En;

    // workspace layout (256B-aligned slabs)
    char* ws = (char*)d_ws;
    size_t off = 0;
    auto alloc = [&](size_t bytes) { size_t o = off; off += (bytes + 255) & ~(size_t)255; return o; };
    int*    cursor = (int*)(ws + alloc((size_t)N * 4));
    int*    csr    = (int*)(ws + alloc((size_t)N * CAP * 4));
    float*  dinv   = (float*)(ws + alloc((size_t)N * 4));
    __half* xs     = (__half*)(ws + alloc((size_t)N * HIDN * 2));
    float*  agg1   = (float*)(ws + alloc((size_t)N * HIDN * 4));
    __half* xl2s   = (__half*)(ws + alloc((size_t)N * HIDN * 2));
    float*  agg2   = (float*)(ws + alloc((size_t)N * HIDN * 4));
    __half* gt     = (__half*)(ws + alloc((size_t)N * HIDN * 2));
    __half* gb     = (__half*)(ws + alloc((size_t)N * HIDN * 2));

    // ---- bucketed CSR build: 4 dst-range sweeps ----
    hipMemsetAsync(cursor, 0, (size_t)N * 4, stream);
    {
        int grid = (Ep + 255) / 256;
        for (int s = 0; s < 4; ++s) {
            int lo = (int)((size_t)N * s / 4);
            int hi = (int)((size_t)N * (s + 1) / 4);
            k_fill_sweep<<<grid, 256, 0, stream>>>(ps, pd, Ep, lo, hi, cursor, csr);
        }
    }
    k_prep<<<(N + 255) / 256, 256, 0, stream>>>(cursor, N, dinv,
                                                (const float4*)x, (Half4*)xs);

    // ---- layer 1 ----
    k_gather_h<<<(N * 4 + 255) / 256, 256, 0, stream>>>(
        (const float4*)xs, dinv, cursor, csr, N, (float4*)agg1);
    k_mlp1<<<(N + 31) / 32, 256, 0, stream>>>(
        (const float4*)agg1, dinv, W1, b1, W2, N, xl2s);

    // ---- layer 2 ----
    k_gather_h<<<(N * 4 + 255) / 256, 256, 0, stream>>>(
        (const float4*)xl2s, dinv, cursor, csr, N, (float4*)agg2);
    k_mlp2<<<(N + 31) / 32, 256, 0, stream>>>(
        (const float4*)agg2, b2, Wm1, N, gt, gb);

    // ---- edge MLP over pos+neg edges (single dispatch) ----
    {
        int E = Ep + En;
        int P = (E + 1) / 2;
        size_t threads = (size_t)P * 4;
        k_edge<<<(int)((threads + 255) / 256), 256, 0, stream>>>(
            ps, pd, Ep, ns, nd, En, P,
            (const float4*)gt, (const float4*)gb,
            bm1, Wm2, bm2, (float*)d_out);
    }
}